// Round 16
// baseline (122.969 us; speedup 1.0000x reference)
//
#include <hip/hip_runtime.h>
#include <hip/hip_bf16.h>
#include <math.h>

#define B_    64
#define TQ    32
#define TD    4096
#define HDIM  300
#define NB    29      // histogram bins
#define NFEAT 30      // 29 bins + exact-match feature
#define NKT   19      // ktiles of 16 (K padded 300 -> 304)
#define THREADS 256
#define NCH   2       // chunks per block
#define DPB   128     // d-rows per block (2 chunks x 64)
#define RDEP  8       // ring depth
#define NBUCK 1024    // token buckets (tok>>7 < 782)
#define VROW  100000  // vocab rows
#define H16   304     // fp16 row length (padded, 608 B)
#define QF_SLOTS (NKT * 2 * 64)        // half4 A-frag slots per batch = 2432
#define QF_F4    (QF_SLOTS / 2)        // = 1216 float4
#define QF_BYTES (QF_SLOTS * 8)        // 19456 B per batch

typedef _Float16 half4 __attribute__((ext_vector_type(4)));
typedef float    f32x4 __attribute__((ext_vector_type(4)));

// bin upper bounds: jnp.linspace(-1,1,30)[1:], ub[k] = -1 + 2(k+1)/29
__device__ __forceinline__ float ubf(int k) {
    return (float)(-1.0 + (2.0 * (double)(k + 1)) / 29.0);
}

// bin one similarity value into the per-block LDS histogram
__device__ __forceinline__ void bin_one(float sim, unsigned* s_hist, int q) {
    if (sim > 0.999f && sim < 1.001f) {
        // only exact token matches land here; true sim < 1.0 strictly -> bin 28
        atomicAdd(&s_hist[q * NFEAT + 28], 1u);
        atomicAdd(&s_hist[q * NFEAT + 29], 1u);   // exact-match feature
    } else {
        int idx = (int)((sim + 1.0f) * 14.5f);    // guess, then exact fixup
        idx = idx < 0 ? 0 : (idx > NB ? NB : idx);
        while (idx < NB && sim >= ubf(idx)) ++idx;
        while (idx > 0 && sim < ubf(idx - 1)) --idx;
        if (idx < NB) atomicAdd(&s_hist[q * NFEAT + idx], 1u);
    }
}

// ---------------- emb fp32 -> fp16 table (streamed, coalesced) ----------------
// Rows padded to 304 halfs (608 B): pad = 0 contributes nothing to dot or norm
// and removes the k-tail guard in k_main. RTE rounding matches k_qfrag's A-frag
// conversion, so exact-token-match q/d fragments stay bit-identical.
__global__ void k_conv(const float* __restrict__ emb, _Float16* __restrict__ emb16) {
    const long long total = (long long)VROW * (H16 / 4);     // 7.6M half4 chunks
    for (long long c = (long long)blockIdx.x * blockDim.x + threadIdx.x;
         c < total; c += (long long)gridDim.x * blockDim.x) {
        const int r = (int)(c / (H16 / 4));
        const int j = (int)(c - (long long)r * (H16 / 4));
        const int kg = j * 4;
        half4 h = {(_Float16)0.f, (_Float16)0.f, (_Float16)0.f, (_Float16)0.f};
        if (kg < HDIM) {    // kg <= 296 -> floats kg..kg+3 all < 300
            float4 v = *(const float4*)(emb + (size_t)r * HDIM + kg);
            h = (half4){(_Float16)v.x, (_Float16)v.y, (_Float16)v.z, (_Float16)v.w};
        }
        *(half4*)(emb16 + (size_t)r * H16 + kg) = h;
    }
}

// ---------------- d-token bucket sort (per batch) -----------------------------
// Histogram/norms/mask are permutation-invariant over d (ghist is a sum of
// integer atomic increments), so any d order is valid; ascending-token order
// makes duplicates cache-adjacent and block ranges ~contiguous in the table.
__global__ void k_sort(const int* __restrict__ sent, int* __restrict__ sorted) {
    const int b = blockIdx.x;
    const int t = threadIdx.x;          // 256
    const int lane = t & 63, wv = t >> 6;
    __shared__ unsigned cnt[NBUCK];
    __shared__ unsigned wtot[4];
    for (int i = t; i < NBUCK; i += 256) cnt[i] = 0u;
    __syncthreads();
    int tk[16];
#pragma unroll
    for (int j = 0; j < 16; ++j) tk[j] = sent[b * TD + j * 256 + t];
#pragma unroll
    for (int j = 0; j < 16; ++j) atomicAdd(&cnt[(unsigned)tk[j] >> 7], 1u);
    __syncthreads();
    unsigned c0 = cnt[t * 4], c1 = cnt[t * 4 + 1], c2 = cnt[t * 4 + 2], c3 = cnt[t * 4 + 3];
    unsigned s = c0 + c1 + c2 + c3;
    unsigned v = s;
#pragma unroll
    for (int d = 1; d < 64; d <<= 1) {
        unsigned n = __shfl_up(v, d, 64);
        if (lane >= d) v += n;
    }
    if (lane == 63) wtot[wv] = v;
    __syncthreads();
    unsigned wbase = 0;
    for (int w = 0; w < wv; ++w) wbase += wtot[w];
    const unsigned base = wbase + v - s;
    __syncthreads();
    cnt[t * 4]     = base;
    cnt[t * 4 + 1] = base + c0;
    cnt[t * 4 + 2] = base + c0 + c1;
    cnt[t * 4 + 3] = base + c0 + c1 + c2;
    __syncthreads();
#pragma unroll
    for (int j = 0; j < 16; ++j) {
        unsigned pos = atomicAdd(&cnt[(unsigned)tk[j] >> 7], 1u);
        sorted[b * TD + pos] = tk[j];
    }
}

// ---------------- q pre-pass: gather q rows ONCE per batch -> fp16 A-frags ----
__global__ void k_qfrag(const int* __restrict__ qsent, const float* __restrict__ emb,
                        _Float16* __restrict__ qf, float* __restrict__ invq,
                        unsigned* __restrict__ ghist) {
    const int b = blockIdx.x;
    const int t = threadIdx.x;
    const int row = t & 31, seg = t >> 5;
    __shared__ float pn[8][TQ];
    for (int i = t; i < TQ * NFEAT; i += 256) ghist[b * TQ * NFEAT + i] = 0u;
    const int tok = qsent[b * TQ + row];
    const float* p = emb + (size_t)tok * HDIM;
    _Float16* qfb = qf + (size_t)b * (QF_SLOTS * 4);
    float n = 0.f;
#pragma unroll
    for (int i = 0; i < 10; ++i) {                 // jf = seg*10 + i, valid < 76
        const int jf = seg * 10 + i;
        if (jf < 76) {
            const int kg = jf * 4;
            float4 v = make_float4(0.f, 0.f, 0.f, 0.f);
            if (kg < 297) v = *(const float4*)(p + kg);    // kg<=296 covers k<=299
            n = fmaf(v.x, v.x, n); n = fmaf(v.y, v.y, n);
            n = fmaf(v.z, v.z, n); n = fmaf(v.w, v.w, n);
            half4 h = {(_Float16)v.x, (_Float16)v.y, (_Float16)v.z, (_Float16)v.w};
            const int kt = jf >> 2, g = jf & 3;
            const int slot = (kt * 2 + (row >> 4)) * 64 + (row & 15) + 16 * g;
            *(half4*)&qfb[slot * 4] = h;
        }
    }
    pn[seg][row] = n;
    __syncthreads();
    if (t < TQ) {
        float s = ((pn[0][t] + pn[1][t]) + (pn[2][t] + pn[3][t]))
                + ((pn[4][t] + pn[5][t]) + (pn[6][t] + pn[7][t]));
        invq[b * TQ + t] = 1.0f / (sqrtf(s + 1e-7f) + 1e-7f);
    }
}

// ---------------- main (fp16 table): register-streamed MFMA + histogram -------
// r15 structure; d-rows gathered from the fp16 table: 8 B/lane/kt (half the
// bytes and lines through the cache path that r11-r15 showed is the wall).
// Pad rows (k 300..303 = 0) remove the tail guard. d-norms accumulate the
// SAME fp16 values the MFMA consumes -> exact-match sim = 1 - O(1e-7), safely
// inside the (0.999, 1.001) window; boundary flips stay ~1e-5-scale.
__global__ __launch_bounds__(THREADS) void k_main_f16(
        const int* __restrict__ sorted, const _Float16* __restrict__ emb16,
        const _Float16* __restrict__ qf, const float* __restrict__ invq,
        unsigned* __restrict__ ghist) {
    __shared__ __align__(16) _Float16 afr[QF_SLOTS * 4];   // 19456 B A-frags
    __shared__ float    s_iq[TQ];
    __shared__ unsigned s_hist[TQ * NFEAT];

    const int b    = blockIdx.x >> 5;
    const int d0   = (blockIdx.x & 31) * DPB;
    const int tid  = threadIdx.x;
    const int wid  = tid >> 6;
    const int lane = tid & 63;

    const int g4   = lane >> 4;              // k-group 0..3
    const int r16  = lane & 15;

    int tok[NCH];
    const _Float16* bp[NCH];
#pragma unroll
    for (int ch = 0; ch < NCH; ++ch) {
        tok[ch] = sorted[b * TD + d0 + ch * 64 + wid * 16 + r16];
        bp[ch]  = emb16 + (size_t)tok[ch] * H16 + g4 * 4;
    }

    auto ldBg = [&](int g) -> half4 {        // no guard: rows padded to 304
        const int ch = g / NKT, kt = g - ch * NKT;
        return *(const half4*)(bp[ch] + kt * 16);
    };

    // ---- issue first ring loads (latency hides under A-stage below)
    half4 pre[RDEP];
#pragma unroll
    for (int p = 0; p < RDEP; ++p) pre[p] = ldBg(p);

    // ---- hist init + A-frag stage (1216 float4, linear, L2-hot) + s_iq
    for (int i = tid; i < TQ * NFEAT; i += THREADS) s_hist[i] = 0u;
    {
        const float4* qfp = (const float4*)(qf + (size_t)b * (QF_SLOTS * 4));
        float4* afp = (float4*)afr;
        for (int i = tid; i < QF_F4; i += THREADS) afp[i] = qfp[i];
    }
    if (tid < TQ) s_iq[tid] = invq[b * TQ + tid];
    __syncthreads();

#pragma unroll
    for (int ch = 0; ch < NCH; ++ch) {
        f32x4 acc0 = {0.f, 0.f, 0.f, 0.f};
        f32x4 acc1 = {0.f, 0.f, 0.f, 0.f};
        float nd = 0.f;
#pragma unroll
        for (int kt = 0; kt < NKT; ++kt) {
            const int g = ch * NKT + kt;
            half4 hb = pre[g % RDEP];
            if (g + RDEP < NCH * NKT) pre[g % RDEP] = ldBg(g + RDEP);
            const float x0 = (float)hb[0], x1 = (float)hb[1];
            const float x2 = (float)hb[2], x3 = (float)hb[3];
            nd = fmaf(x0, x0, nd); nd = fmaf(x1, x1, nd);
            nd = fmaf(x2, x2, nd); nd = fmaf(x3, x3, nd);
            half4 a0 = *(const half4*)&afr[((kt * 2 + 0) * 64 + lane) * 4];
            half4 a1 = *(const half4*)&afr[((kt * 2 + 1) * 64 + lane) * 4];
            acc0 = __builtin_amdgcn_mfma_f32_16x16x16f16(a0, hb, acc0, 0, 0, 0);
            acc1 = __builtin_amdgcn_mfma_f32_16x16x16f16(a1, hb, acc1, 0, 0, 0);
        }
        float t = nd;
        t += __shfl_xor(t, 16, 64);
        t += __shfl_xor(t, 32, 64);
        const float idv = 1.0f / (sqrtf(t + 1e-7f) + 1e-7f);
        if (tok[ch] != 0) {        // masked doc: +1e7 -> dropped everywhere
#pragma unroll
            for (int r = 0; r < 4; ++r) {
                const int q0 = g4 * 4 + r;
                bin_one(acc0[r] * s_iq[q0] * idv, s_hist, q0);
                const int q1 = 16 + g4 * 4 + r;
                bin_one(acc1[r] * s_iq[q1] * idv, s_hist, q1);
            }
        }
    }
    __syncthreads();
    for (int i = tid; i < TQ * NFEAT; i += THREADS) {
        unsigned v = s_hist[i];
        if (v) atomicAdd(&ghist[b * TQ * NFEAT + i], v);
    }
}

// ---------------- main (fp32 fallback, byte-identical to r15) -----------------
__global__ __launch_bounds__(THREADS) void k_main_f32(
        const int* __restrict__ sorted, const float* __restrict__ emb,
        const _Float16* __restrict__ qf, const float* __restrict__ invq,
        unsigned* __restrict__ ghist) {
    __shared__ __align__(16) _Float16 afr[QF_SLOTS * 4];
    __shared__ float    s_iq[TQ];
    __shared__ unsigned s_hist[TQ * NFEAT];

    const int b    = blockIdx.x >> 5;
    const int d0   = (blockIdx.x & 31) * DPB;
    const int tid  = threadIdx.x;
    const int wid  = tid >> 6;
    const int lane = tid & 63;
    const int g4   = lane >> 4;
    const int r16  = lane & 15;

    int tok[NCH];
    const float* bp[NCH];
#pragma unroll
    for (int ch = 0; ch < NCH; ++ch) {
        tok[ch] = sorted[b * TD + d0 + ch * 64 + wid * 16 + r16];
        bp[ch]  = emb + (size_t)tok[ch] * HDIM + g4 * 4;
    }
    auto ldBg = [&](int g) -> float4 {
        const int ch = g / NKT, kt = g - ch * NKT;
        if (kt == 18 && g4 == 3) return make_float4(0.f, 0.f, 0.f, 0.f);
        return *(const float4*)(bp[ch] + kt * 16);
    };
    float4 pre[RDEP];
#pragma unroll
    for (int p = 0; p < RDEP; ++p) pre[p] = ldBg(p);

    for (int i = tid; i < TQ * NFEAT; i += THREADS) s_hist[i] = 0u;
    {
        const float4* qfp = (const float4*)(qf + (size_t)b * (QF_SLOTS * 4));
        float4* afp = (float4*)afr;
        for (int i = tid; i < QF_F4; i += THREADS) afp[i] = qfp[i];
    }
    if (tid < TQ) s_iq[tid] = invq[b * TQ + tid];
    __syncthreads();

#pragma unroll
    for (int ch = 0; ch < NCH; ++ch) {
        f32x4 acc0 = {0.f, 0.f, 0.f, 0.f};
        f32x4 acc1 = {0.f, 0.f, 0.f, 0.f};
        float nd = 0.f;
#pragma unroll
        for (int kt = 0; kt < NKT; ++kt) {
            const int g = ch * NKT + kt;
            float4 v = pre[g % RDEP];
            if (g + RDEP < NCH * NKT) pre[g % RDEP] = ldBg(g + RDEP);
            nd = fmaf(v.x, v.x, nd); nd = fmaf(v.y, v.y, nd);
            nd = fmaf(v.z, v.z, nd); nd = fmaf(v.w, v.w, nd);
            half4 hb = {(_Float16)v.x, (_Float16)v.y, (_Float16)v.z, (_Float16)v.w};
            half4 a0 = *(const half4*)&afr[((kt * 2 + 0) * 64 + lane) * 4];
            half4 a1 = *(const half4*)&afr[((kt * 2 + 1) * 64 + lane) * 4];
            acc0 = __builtin_amdgcn_mfma_f32_16x16x16f16(a0, hb, acc0, 0, 0, 0);
            acc1 = __builtin_amdgcn_mfma_f32_16x16x16f16(a1, hb, acc1, 0, 0, 0);
        }
        float t = nd;
        t += __shfl_xor(t, 16, 64);
        t += __shfl_xor(t, 32, 64);
        const float idv = 1.0f / (sqrtf(t + 1e-7f) + 1e-7f);
        if (tok[ch] != 0) {
#pragma unroll
            for (int r = 0; r < 4; ++r) {
                const int q0 = g4 * 4 + r;
                bin_one(acc0[r] * s_iq[q0] * idv, s_hist, q0);
                const int q1 = 16 + g4 * 4 + r;
                bin_one(acc1[r] * s_iq[q1] * idv, s_hist, q1);
            }
        }
    }
    __syncthreads();
    for (int i = tid; i < TQ * NFEAT; i += THREADS) {
        unsigned v = s_hist[i];
        if (v) atomicAdd(&ghist[b * TQ * NFEAT + i], v);
    }
}

// ---------------- finish: log + MLP + gate softmax ----------------
__global__ void k_finish(const unsigned* __restrict__ ghist,
                         const int* __restrict__ qsent, const float* __restrict__ idf,
                         const float* __restrict__ w1, const float* __restrict__ b1,
                         const float* __restrict__ w2, const float* __restrict__ b2,
                         const float* __restrict__ gw, const float* __restrict__ ow,
                         const float* __restrict__ ob, float* __restrict__ out) {
    int b = blockIdx.x;
    int lane = threadIdx.x;   // 64 threads, lanes 0..31 active
    float ffw = 0.f;
    float logit = -3.0e38f;
    if (lane < TQ) {
        const unsigned* h = ghist + (b * TQ + lane) * NFEAT;
        float f[NFEAT];
        for (int k = 0; k < NFEAT; ++k) f[k] = logf((float)h[k] + 1.0f);
        float s2 = b2[0];
        for (int n = 0; n < 5; ++n) {
            float s = b1[n];
            for (int k = 0; k < NFEAT; ++k) s = fmaf(f[k], w1[k * 5 + n], s);
            s2 = fmaf(tanhf(s), w2[n], s2);
        }
        ffw = tanhf(s2);
        int qt = qsent[b * TQ + lane];
        logit = idf[b * TQ + lane] * gw[0] + (qt == 0 ? -1e7f : 0.f);
    }
    float m = logit;
#pragma unroll
    for (int t = 1; t < 64; t <<= 1) m = fmaxf(m, __shfl_xor(m, t, 64));
    float e = expf(logit - m);            // inactive lanes -> exp(-inf) = 0
    float se = e, sw = e * ffw;
#pragma unroll
    for (int t = 1; t < 64; t <<= 1) {
        se += __shfl_xor(se, t, 64);
        sw += __shfl_xor(sw, t, 64);
    }
    if (lane == 0) out[b] = (sw / se) * ow[0] + ob[0];
}

extern "C" void kernel_launch(void* const* d_in, const int* in_sizes, int n_in,
                              void* d_out, int out_size, void* d_ws, size_t ws_size,
                              hipStream_t stream) {
    const int*   sent  = (const int*)d_in[0];
    const int*   qsent = (const int*)d_in[1];
    const float* idf   = (const float*)d_in[2];
    const float* emb   = (const float*)d_in[3];
    const float* w1    = (const float*)d_in[4];
    const float* b1    = (const float*)d_in[5];
    const float* w2    = (const float*)d_in[6];
    const float* b2    = (const float*)d_in[7];
    const float* gw    = (const float*)d_in[8];
    const float* ow    = (const float*)d_in[9];
    const float* ob    = (const float*)d_in[10];
    float* out = (float*)d_out;

    char* ws = (char*)d_ws;
    unsigned*  ghist  = (unsigned*)ws;                      // 240 KB
    _Float16*  qfrag  = (_Float16*)(ws + (256 << 10));      // 1.22 MB
    float*     invq   = (float*)(ws + (256 << 10) + (size_t)B_ * QF_BYTES);
    int*       sorted = (int*)(ws + (256 << 10) + (size_t)B_ * QF_BYTES
                               + (size_t)B_ * TQ * 4);      // 1 MB
    const size_t emb16_off = 4u << 20;                      // 4 MB aligned
    _Float16*  emb16  = (_Float16*)(ws + emb16_off);
    const size_t need = emb16_off + (size_t)VROW * H16 * 2; // ~64.8 MB

    k_sort<<<B_, 256, 0, stream>>>(sent, sorted);
    k_qfrag<<<B_, 256, 0, stream>>>(qsent, emb, qfrag, invq, ghist);
    if (ws_size >= need) {
        k_conv<<<2048, 256, 0, stream>>>(emb, emb16);
        k_main_f16<<<B_ * (TD / DPB), THREADS, 0, stream>>>(sorted, emb16, qfrag, invq, ghist);
    } else {
        k_main_f32<<<B_ * (TD / DPB), THREADS, 0, stream>>>(sorted, emb, qfrag, invq, ghist);
    }
    k_finish<<<B_, 64, 0, stream>>>(ghist, qsent, idf, w1, b1, w2, b2, gw, ow, ob, out);
}

// Round 17
// 85.912 us; speedup vs baseline: 1.4313x; 1.4313x over previous
//
#include <hip/hip_runtime.h>
#include <hip/hip_bf16.h>
#include <math.h>

#define B_    64
#define TQ    32
#define TD    4096
#define HDIM  300
#define NB    29      // histogram bins
#define NFEAT 30      // 29 bins + exact-match feature
#define NKT   19      // ktiles of 16 (K padded 300 -> 304)
#define THREADS 256
#define NCH   2       // chunks per block
#define DPB   128     // d-rows per block (2 chunks x 64)
#define RDEP  16      // ring depth (r17: 8 -> 16, covers ~2x the gather latency)
#define NBUCK 1024    // token buckets (tok>>7 < 782)
#define QF_SLOTS (NKT * 2 * 64)        // half4 A-frag slots per batch = 2432
#define QF_F4    (QF_SLOTS / 2)        // = 1216 float4
#define QF_BYTES (QF_SLOTS * 8)        // 19456 B per batch

typedef _Float16 half4 __attribute__((ext_vector_type(4)));
typedef float    f32x4 __attribute__((ext_vector_type(4)));

// bin upper bounds: jnp.linspace(-1,1,30)[1:], ub[k] = -1 + 2(k+1)/29
__device__ __forceinline__ float ubf(int k) {
    return (float)(-1.0 + (2.0 * (double)(k + 1)) / 29.0);
}

// bin one similarity value into the per-block LDS histogram
__device__ __forceinline__ void bin_one(float sim, unsigned* s_hist, int q) {
    if (sim > 0.999f && sim < 1.001f) {
        // only exact token matches land here; true sim < 1.0 strictly -> bin 28
        atomicAdd(&s_hist[q * NFEAT + 28], 1u);
        atomicAdd(&s_hist[q * NFEAT + 29], 1u);   // exact-match feature
    } else {
        int idx = (int)((sim + 1.0f) * 14.5f);    // guess, then exact fixup
        idx = idx < 0 ? 0 : (idx > NB ? NB : idx);
        while (idx < NB && sim >= ubf(idx)) ++idx;
        while (idx > 0 && sim < ubf(idx - 1)) --idx;
        if (idx < NB) atomicAdd(&s_hist[q * NFEAT + idx], 1u);
    }
}

// ---------------- d-token bucket sort (per batch) -----------------------------
// Histogram/norms/mask are permutation-invariant over d (ghist is a sum of
// integer atomic increments), so any d order is valid; ascending-token order
// makes duplicates cache-adjacent and block ranges ~contiguous in the table.
__global__ void k_sort(const int* __restrict__ sent, int* __restrict__ sorted) {
    const int b = blockIdx.x;
    const int t = threadIdx.x;          // 256
    const int lane = t & 63, wv = t >> 6;
    __shared__ unsigned cnt[NBUCK];
    __shared__ unsigned wtot[4];
    for (int i = t; i < NBUCK; i += 256) cnt[i] = 0u;
    __syncthreads();
    int tk[16];
#pragma unroll
    for (int j = 0; j < 16; ++j) tk[j] = sent[b * TD + j * 256 + t];
#pragma unroll
    for (int j = 0; j < 16; ++j) atomicAdd(&cnt[(unsigned)tk[j] >> 7], 1u);
    __syncthreads();
    unsigned c0 = cnt[t * 4], c1 = cnt[t * 4 + 1], c2 = cnt[t * 4 + 2], c3 = cnt[t * 4 + 3];
    unsigned s = c0 + c1 + c2 + c3;
    unsigned v = s;
#pragma unroll
    for (int d = 1; d < 64; d <<= 1) {
        unsigned n = __shfl_up(v, d, 64);
        if (lane >= d) v += n;
    }
    if (lane == 63) wtot[wv] = v;
    __syncthreads();
    unsigned wbase = 0;
    for (int w = 0; w < wv; ++w) wbase += wtot[w];
    const unsigned base = wbase + v - s;
    __syncthreads();
    cnt[t * 4]     = base;
    cnt[t * 4 + 1] = base + c0;
    cnt[t * 4 + 2] = base + c0 + c1;
    cnt[t * 4 + 3] = base + c0 + c1 + c2;
    __syncthreads();
#pragma unroll
    for (int j = 0; j < 16; ++j) {
        unsigned pos = atomicAdd(&cnt[(unsigned)tk[j] >> 7], 1u);
        sorted[b * TD + pos] = tk[j];
    }
}

// ---------------- q pre-pass: gather q rows ONCE per batch -> fp16 A-frags ----
__global__ void k_qfrag(const int* __restrict__ qsent, const float* __restrict__ emb,
                        _Float16* __restrict__ qf, float* __restrict__ invq,
                        unsigned* __restrict__ ghist) {
    const int b = blockIdx.x;
    const int t = threadIdx.x;
    const int row = t & 31, seg = t >> 5;
    __shared__ float pn[8][TQ];
    for (int i = t; i < TQ * NFEAT; i += 256) ghist[b * TQ * NFEAT + i] = 0u;
    const int tok = qsent[b * TQ + row];
    const float* p = emb + (size_t)tok * HDIM;
    _Float16* qfb = qf + (size_t)b * (QF_SLOTS * 4);
    float n = 0.f;
#pragma unroll
    for (int i = 0; i < 10; ++i) {                 // jf = seg*10 + i, valid < 76
        const int jf = seg * 10 + i;
        if (jf < 76) {
            const int kg = jf * 4;
            float4 v = make_float4(0.f, 0.f, 0.f, 0.f);
            if (kg < 297) v = *(const float4*)(p + kg);    // kg<=296 covers k<=299
            n = fmaf(v.x, v.x, n); n = fmaf(v.y, v.y, n);
            n = fmaf(v.z, v.z, n); n = fmaf(v.w, v.w, n);
            half4 h = {(_Float16)v.x, (_Float16)v.y, (_Float16)v.z, (_Float16)v.w};
            const int kt = jf >> 2, g = jf & 3;
            const int slot = (kt * 2 + (row >> 4)) * 64 + (row & 15) + 16 * g;
            *(half4*)&qfb[slot * 4] = h;
        }
    }
    pn[seg][row] = n;
    __syncthreads();
    if (t < TQ) {
        float s = ((pn[0][t] + pn[1][t]) + (pn[2][t] + pn[3][t]))
                + ((pn[4][t] + pn[5][t]) + (pn[6][t] + pn[7][t]));
        invq[b * TQ + t] = 1.0f / (sqrtf(s + 1e-7f) + 1e-7f);
    }
}

// ---------------- main: persistent-chunk register-streamed fp16-MFMA ----------
// r15 structure, ring depth 16 (the single change): r11-r16 showed duration
// invariant to bytes (63-179 MB), occupancy (20-39%), sort order, and fp16 vs
// fp32 -- the one constant was the per-lane dependent chain (consume pre[g%R]
// loaded R steps earlier; R=8 covers ~450 cyc of ~1300 cyc gather latency).
// R=16 doubles the latency cover; r16 proved occupancy loss from extra VGPRs
// is free, so deeper ILP is pure upside if the chain is the wall.
// Arithmetic identical to r15 -> absmax bit-identical (1.907349e-06).
__global__ __launch_bounds__(THREADS) void k_main(
        const int* __restrict__ sorted, const float* __restrict__ emb,
        const _Float16* __restrict__ qf, const float* __restrict__ invq,
        unsigned* __restrict__ ghist) {
    __shared__ __align__(16) _Float16 afr[QF_SLOTS * 4];   // 19456 B A-frags
    __shared__ float    s_iq[TQ];
    __shared__ unsigned s_hist[TQ * NFEAT];

    const int b    = blockIdx.x >> 5;
    const int d0   = (blockIdx.x & 31) * DPB;
    const int tid  = threadIdx.x;
    const int wid  = tid >> 6;
    const int lane = tid & 63;

    const int g4   = lane >> 4;              // k-group 0..3
    const int r16  = lane & 15;

    int tok[NCH];
    const float* bp[NCH];
#pragma unroll
    for (int ch = 0; ch < NCH; ++ch) {
        tok[ch] = sorted[b * TD + d0 + ch * 64 + wid * 16 + r16];
        bp[ch]  = emb + (size_t)tok[ch] * HDIM + g4 * 4;
    }

    // guarded B load by global step g (compile-time ch/kt after unroll);
    // kt=18,g4=3 would read k 300..303 (OOB of row) -> zero
    auto ldBg = [&](int g) -> float4 {
        const int ch = g / NKT, kt = g - ch * NKT;
        if (kt == 18 && g4 == 3) return make_float4(0.f, 0.f, 0.f, 0.f);
        return *(const float4*)(bp[ch] + kt * 16);
    };

    // ---- issue first ring loads (latency hides under A-stage below)
    float4 pre[RDEP];
#pragma unroll
    for (int p = 0; p < RDEP; ++p) pre[p] = ldBg(p);

    // ---- hist init + A-frag stage (1216 float4, linear, L2-hot) + s_iq
    for (int i = tid; i < TQ * NFEAT; i += THREADS) s_hist[i] = 0u;
    {
        const float4* qfp = (const float4*)(qf + (size_t)b * (QF_SLOTS * 4));
        float4* afp = (float4*)afr;
        for (int i = tid; i < QF_F4; i += THREADS) afp[i] = qfp[i];
    }
    if (tid < TQ) s_iq[tid] = invq[b * TQ + tid];
    __syncthreads();

#pragma unroll
    for (int ch = 0; ch < NCH; ++ch) {
        f32x4 acc0 = {0.f, 0.f, 0.f, 0.f};
        f32x4 acc1 = {0.f, 0.f, 0.f, 0.f};
        float nd = 0.f;
#pragma unroll
        for (int kt = 0; kt < NKT; ++kt) {
            const int g = ch * NKT + kt;
            float4 v = pre[g % RDEP];
            if (g + RDEP < NCH * NKT) pre[g % RDEP] = ldBg(g + RDEP);
            nd = fmaf(v.x, v.x, nd); nd = fmaf(v.y, v.y, nd);
            nd = fmaf(v.z, v.z, nd); nd = fmaf(v.w, v.w, nd);
            half4 hb = {(_Float16)v.x, (_Float16)v.y, (_Float16)v.z, (_Float16)v.w};
            half4 a0 = *(const half4*)&afr[((kt * 2 + 0) * 64 + lane) * 4];
            half4 a1 = *(const half4*)&afr[((kt * 2 + 1) * 64 + lane) * 4];
            acc0 = __builtin_amdgcn_mfma_f32_16x16x16f16(a0, hb, acc0, 0, 0, 0);
            acc1 = __builtin_amdgcn_mfma_f32_16x16x16f16(a1, hb, acc1, 0, 0, 0);
        }
        // ---- per-chunk epilogue: norm tree (lanes l^16, l^32) + bins
        float t = nd;
        t += __shfl_xor(t, 16, 64);
        t += __shfl_xor(t, 32, 64);
        const float idv = 1.0f / (sqrtf(t + 1e-7f) + 1e-7f);
        if (tok[ch] != 0) {        // masked doc: +1e7 -> dropped everywhere
#pragma unroll
            for (int r = 0; r < 4; ++r) {
                const int q0 = g4 * 4 + r;
                bin_one(acc0[r] * s_iq[q0] * idv, s_hist, q0);
                const int q1 = 16 + g4 * 4 + r;
                bin_one(acc1[r] * s_iq[q1] * idv, s_hist, q1);
            }
        }
    }
    __syncthreads();
    for (int i = tid; i < TQ * NFEAT; i += THREADS) {
        unsigned v = s_hist[i];
        if (v) atomicAdd(&ghist[b * TQ * NFEAT + i], v);
    }
}

// ---------------- finish: log + MLP + gate softmax ----------------
__global__ void k_finish(const unsigned* __restrict__ ghist,
                         const int* __restrict__ qsent, const float* __restrict__ idf,
                         const float* __restrict__ w1, const float* __restrict__ b1,
                         const float* __restrict__ w2, const float* __restrict__ b2,
                         const float* __restrict__ gw, const float* __restrict__ ow,
                         const float* __restrict__ ob, float* __restrict__ out) {
    int b = blockIdx.x;
    int lane = threadIdx.x;   // 64 threads, lanes 0..31 active
    float ffw = 0.f;
    float logit = -3.0e38f;
    if (lane < TQ) {
        const unsigned* h = ghist + (b * TQ + lane) * NFEAT;
        float f[NFEAT];
        for (int k = 0; k < NFEAT; ++k) f[k] = logf((float)h[k] + 1.0f);
        float s2 = b2[0];
        for (int n = 0; n < 5; ++n) {
            float s = b1[n];
            for (int k = 0; k < NFEAT; ++k) s = fmaf(f[k], w1[k * 5 + n], s);
            s2 = fmaf(tanhf(s), w2[n], s2);
        }
        ffw = tanhf(s2);
        int qt = qsent[b * TQ + lane];
        logit = idf[b * TQ + lane] * gw[0] + (qt == 0 ? -1e7f : 0.f);
    }
    float m = logit;
#pragma unroll
    for (int t = 1; t < 64; t <<= 1) m = fmaxf(m, __shfl_xor(m, t, 64));
    float e = expf(logit - m);            // inactive lanes -> exp(-inf) = 0
    float se = e, sw = e * ffw;
#pragma unroll
    for (int t = 1; t < 64; t <<= 1) {
        se += __shfl_xor(se, t, 64);
        sw += __shfl_xor(sw, t, 64);
    }
    if (lane == 0) out[b] = (sw / se) * ow[0] + ob[0];
}

extern "C" void kernel_launch(void* const* d_in, const int* in_sizes, int n_in,
                              void* d_out, int out_size, void* d_ws, size_t ws_size,
                              hipStream_t stream) {
    const int*   sent  = (const int*)d_in[0];
    const int*   qsent = (const int*)d_in[1];
    const float* idf   = (const float*)d_in[2];
    const float* emb   = (const float*)d_in[3];
    const float* w1    = (const float*)d_in[4];
    const float* b1    = (const float*)d_in[5];
    const float* w2    = (const float*)d_in[6];
    const float* b2    = (const float*)d_in[7];
    const float* gw    = (const float*)d_in[8];
    const float* ow    = (const float*)d_in[9];
    const float* ob    = (const float*)d_in[10];
    float* out = (float*)d_out;

    char* ws = (char*)d_ws;
    unsigned*  ghist  = (unsigned*)ws;                      // 240 KB
    _Float16*  qfrag  = (_Float16*)(ws + (256 << 10));      // 1.22 MB
    float*     invq   = (float*)(ws + (256 << 10) + (size_t)B_ * QF_BYTES);
    int*       sorted = (int*)(ws + (256 << 10) + (size_t)B_ * QF_BYTES
                               + (size_t)B_ * TQ * 4);      // 1 MB

    k_sort<<<B_, 256, 0, stream>>>(sent, sorted);
    k_qfrag<<<B_, 256, 0, stream>>>(qsent, emb, qfrag, invq, ghist);
    k_main<<<B_ * (TD / DPB), THREADS, 0, stream>>>(sorted, emb, qfrag, invq, ghist);
    k_finish<<<B_, 64, 0, stream>>>(ghist, qsent, idf, w1, b1, w2, b2, gw, ow, ob, out);
}

// Round 18
// 79.184 us; speedup vs baseline: 1.5529x; 1.0850x over previous
//
#include <hip/hip_runtime.h>
#include <hip/hip_bf16.h>
#include <math.h>

#define B_    64
#define TQ    32
#define TD    4096
#define HDIM  300
#define NB    29      // histogram bins
#define NFEAT 30      // 29 bins + exact-match feature
#define NKT   19      // ktiles of 16 (K padded 300 -> 304)
#define THREADS 256
#define NCH   2       // chunks per block
#define DPB   128     // d-rows per block (2 chunks x 64)
#define RDEP  8       // ring depth (r15 best; 16 regressed r17)
#define NBUCK 1024    // token buckets (tok>>7 < 782)
#define QF_SLOTS (NKT * 2 * 64)        // half4 A-frag slots per batch = 2432
#define QF_F4    (QF_SLOTS / 2)        // = 1216 float4
#define QF_BYTES (QF_SLOTS * 8)        // 19456 B per batch

typedef _Float16 half4 __attribute__((ext_vector_type(4)));
typedef float    f32x4 __attribute__((ext_vector_type(4)));

// bin upper bounds: jnp.linspace(-1,1,30)[1:], ub[k] = -1 + 2(k+1)/29
__device__ __forceinline__ float ubf(int k) {
    return (float)(-1.0 + (2.0 * (double)(k + 1)) / 29.0);
}

// bin one similarity value into the per-block LDS histogram
__device__ __forceinline__ void bin_one(float sim, unsigned* s_hist, int q) {
    if (sim > 0.999f && sim < 1.001f) {
        // only exact token matches land here; true sim < 1.0 strictly -> bin 28
        atomicAdd(&s_hist[q * NFEAT + 28], 1u);
        atomicAdd(&s_hist[q * NFEAT + 29], 1u);   // exact-match feature
    } else {
        int idx = (int)((sim + 1.0f) * 14.5f);    // guess, then exact fixup
        idx = idx < 0 ? 0 : (idx > NB ? NB : idx);
        while (idx < NB && sim >= ubf(idx)) ++idx;
        while (idx > 0 && sim < ubf(idx - 1)) --idx;
        if (idx < NB) atomicAdd(&s_hist[q * NFEAT + idx], 1u);
    }
}

// ---------------- prep: bucket sort (blocks 0..63) + q-frags (blocks 64..127) -
// Sort: histogram/norms/mask are permutation-invariant over d (ghist is a sum
// of integer atomic increments), so ascending-token order is valid and makes
// duplicates cache-adjacent / block ranges contiguous in the table.
// Qfrag: gather q rows once per batch, fp32 loads, 8-partial deterministic
// norm, fp16 A-frag stores (A lane l holds A[l%16][(l/16)*4+j]).
__global__ void k_prep(const int* __restrict__ sent, const int* __restrict__ qsent,
                       const float* __restrict__ emb, int* __restrict__ sorted,
                       _Float16* __restrict__ qf, float* __restrict__ invq,
                       unsigned* __restrict__ ghist) {
    const int t = threadIdx.x;          // 256
    if (blockIdx.x < B_) {
        // ---------- bucket sort for batch b ----------
        const int b = blockIdx.x;
        const int lane = t & 63, wv = t >> 6;
        __shared__ unsigned cnt[NBUCK];
        __shared__ unsigned wtot[4];
        for (int i = t; i < NBUCK; i += 256) cnt[i] = 0u;
        __syncthreads();
        int tk[16];
#pragma unroll
        for (int j = 0; j < 16; ++j) tk[j] = sent[b * TD + j * 256 + t];
#pragma unroll
        for (int j = 0; j < 16; ++j) atomicAdd(&cnt[(unsigned)tk[j] >> 7], 1u);
        __syncthreads();
        unsigned c0 = cnt[t * 4], c1 = cnt[t * 4 + 1], c2 = cnt[t * 4 + 2], c3 = cnt[t * 4 + 3];
        unsigned s = c0 + c1 + c2 + c3;
        unsigned v = s;
#pragma unroll
        for (int d = 1; d < 64; d <<= 1) {
            unsigned n = __shfl_up(v, d, 64);
            if (lane >= d) v += n;
        }
        if (lane == 63) wtot[wv] = v;
        __syncthreads();
        unsigned wbase = 0;
        for (int w = 0; w < wv; ++w) wbase += wtot[w];
        const unsigned base = wbase + v - s;
        __syncthreads();
        cnt[t * 4]     = base;
        cnt[t * 4 + 1] = base + c0;
        cnt[t * 4 + 2] = base + c0 + c1;
        cnt[t * 4 + 3] = base + c0 + c1 + c2;
        __syncthreads();
#pragma unroll
        for (int j = 0; j < 16; ++j) {
            unsigned pos = atomicAdd(&cnt[(unsigned)tk[j] >> 7], 1u);
            sorted[b * TD + pos] = tk[j];
        }
    } else {
        // ---------- q-frags for batch b ----------
        const int b = blockIdx.x - B_;
        const int row = t & 31, seg = t >> 5;
        __shared__ float pn[8][TQ];
        for (int i = t; i < TQ * NFEAT; i += 256) ghist[b * TQ * NFEAT + i] = 0u;
        const int tok = qsent[b * TQ + row];
        const float* p = emb + (size_t)tok * HDIM;
        _Float16* qfb = qf + (size_t)b * (QF_SLOTS * 4);
        float n = 0.f;
#pragma unroll
        for (int i = 0; i < 10; ++i) {             // jf = seg*10 + i, valid < 76
            const int jf = seg * 10 + i;
            if (jf < 76) {
                const int kg = jf * 4;
                float4 v = make_float4(0.f, 0.f, 0.f, 0.f);
                if (kg < 297) v = *(const float4*)(p + kg);  // kg<=296 covers k<=299
                n = fmaf(v.x, v.x, n); n = fmaf(v.y, v.y, n);
                n = fmaf(v.z, v.z, n); n = fmaf(v.w, v.w, n);
                half4 h = {(_Float16)v.x, (_Float16)v.y, (_Float16)v.z, (_Float16)v.w};
                const int kt = jf >> 2, g = jf & 3;
                const int slot = (kt * 2 + (row >> 4)) * 64 + (row & 15) + 16 * g;
                *(half4*)&qfb[slot * 4] = h;
            }
        }
        pn[seg][row] = n;
        __syncthreads();
        if (t < TQ) {
            float s = ((pn[0][t] + pn[1][t]) + (pn[2][t] + pn[3][t]))
                    + ((pn[4][t] + pn[5][t]) + (pn[6][t] + pn[7][t]));
            invq[b * TQ + t] = 1.0f / (sqrtf(s + 1e-7f) + 1e-7f);
        }
    }
}

// ---------------- main: persistent-chunk register-streamed fp16-MFMA ----------
// r15 structure with SLICE-MAJOR block order (the single perf change):
//   b = blockIdx & 63, slice = blockIdx >> 6.
// Co-resident blocks (~1500 of 2048) now share the same sorted-token SLICE of
// the table: instantaneous working set drops from the full 120 MB (batch-major)
// to ~40 MB GPU-wide / ~10 MB per XCD -> the 64 batches re-touching the same
// rows hit L2 instead of L3/HBM. This attacks access LATENCY, the one axis the
// r11-r17 invariance table (bytes, occupancy, order, precision, ring depth)
// never moved. Arithmetic identical to r15 -> absmax bit-identical.
__global__ __launch_bounds__(THREADS) void k_main(
        const int* __restrict__ sorted, const float* __restrict__ emb,
        const _Float16* __restrict__ qf, const float* __restrict__ invq,
        unsigned* __restrict__ ghist) {
    __shared__ __align__(16) _Float16 afr[QF_SLOTS * 4];   // 19456 B A-frags
    __shared__ float    s_iq[TQ];
    __shared__ unsigned s_hist[TQ * NFEAT];

    const int b    = blockIdx.x & 63;            // slice-major decode
    const int d0   = (blockIdx.x >> 6) * DPB;
    const int tid  = threadIdx.x;
    const int wid  = tid >> 6;
    const int lane = tid & 63;

    const int g4   = lane >> 4;              // k-group 0..3
    const int r16  = lane & 15;

    int tok[NCH];
    const float* bp[NCH];
#pragma unroll
    for (int ch = 0; ch < NCH; ++ch) {
        tok[ch] = sorted[b * TD + d0 + ch * 64 + wid * 16 + r16];
        bp[ch]  = emb + (size_t)tok[ch] * HDIM + g4 * 4;
    }

    // guarded B load by global step g (compile-time ch/kt after unroll);
    // kt=18,g4=3 would read k 300..303 (OOB of row) -> zero
    auto ldBg = [&](int g) -> float4 {
        const int ch = g / NKT, kt = g - ch * NKT;
        if (kt == 18 && g4 == 3) return make_float4(0.f, 0.f, 0.f, 0.f);
        return *(const float4*)(bp[ch] + kt * 16);
    };

    // ---- issue first ring loads (latency hides under A-stage below)
    float4 pre[RDEP];
#pragma unroll
    for (int p = 0; p < RDEP; ++p) pre[p] = ldBg(p);

    // ---- hist init + A-frag stage (1216 float4, linear, L2-hot) + s_iq
    for (int i = tid; i < TQ * NFEAT; i += THREADS) s_hist[i] = 0u;
    {
        const float4* qfp = (const float4*)(qf + (size_t)b * (QF_SLOTS * 4));
        float4* afp = (float4*)afr;
        for (int i = tid; i < QF_F4; i += THREADS) afp[i] = qfp[i];
    }
    if (tid < TQ) s_iq[tid] = invq[b * TQ + tid];
    __syncthreads();

#pragma unroll
    for (int ch = 0; ch < NCH; ++ch) {
        f32x4 acc0 = {0.f, 0.f, 0.f, 0.f};
        f32x4 acc1 = {0.f, 0.f, 0.f, 0.f};
        float nd = 0.f;
#pragma unroll
        for (int kt = 0; kt < NKT; ++kt) {
            const int g = ch * NKT + kt;
            float4 v = pre[g % RDEP];
            if (g + RDEP < NCH * NKT) pre[g % RDEP] = ldBg(g + RDEP);
            nd = fmaf(v.x, v.x, nd); nd = fmaf(v.y, v.y, nd);
            nd = fmaf(v.z, v.z, nd); nd = fmaf(v.w, v.w, nd);
            half4 hb = {(_Float16)v.x, (_Float16)v.y, (_Float16)v.z, (_Float16)v.w};
            half4 a0 = *(const half4*)&afr[((kt * 2 + 0) * 64 + lane) * 4];
            half4 a1 = *(const half4*)&afr[((kt * 2 + 1) * 64 + lane) * 4];
            acc0 = __builtin_amdgcn_mfma_f32_16x16x16f16(a0, hb, acc0, 0, 0, 0);
            acc1 = __builtin_amdgcn_mfma_f32_16x16x16f16(a1, hb, acc1, 0, 0, 0);
        }
        // ---- per-chunk epilogue: norm tree (lanes l^16, l^32) + bins
        float t = nd;
        t += __shfl_xor(t, 16, 64);
        t += __shfl_xor(t, 32, 64);
        const float idv = 1.0f / (sqrtf(t + 1e-7f) + 1e-7f);
        if (tok[ch] != 0) {        // masked doc: +1e7 -> dropped everywhere
#pragma unroll
            for (int r = 0; r < 4; ++r) {
                const int q0 = g4 * 4 + r;
                bin_one(acc0[r] * s_iq[q0] * idv, s_hist, q0);
                const int q1 = 16 + g4 * 4 + r;
                bin_one(acc1[r] * s_iq[q1] * idv, s_hist, q1);
            }
        }
    }
    __syncthreads();
    for (int i = tid; i < TQ * NFEAT; i += THREADS) {
        unsigned v = s_hist[i];
        if (v) atomicAdd(&ghist[b * TQ * NFEAT + i], v);
    }
}

// ---------------- finish: log + MLP + gate softmax ----------------
__global__ void k_finish(const unsigned* __restrict__ ghist,
                         const int* __restrict__ qsent, const float* __restrict__ idf,
                         const float* __restrict__ w1, const float* __restrict__ b1,
                         const float* __restrict__ w2, const float* __restrict__ b2,
                         const float* __restrict__ gw, const float* __restrict__ ow,
                         const float* __restrict__ ob, float* __restrict__ out) {
    int b = blockIdx.x;
    int lane = threadIdx.x;   // 64 threads, lanes 0..31 active
    float ffw = 0.f;
    float logit = -3.0e38f;
    if (lane < TQ) {
        const unsigned* h = ghist + (b * TQ + lane) * NFEAT;
        float f[NFEAT];
        for (int k = 0; k < NFEAT; ++k) f[k] = logf((float)h[k] + 1.0f);
        float s2 = b2[0];
        for (int n = 0; n < 5; ++n) {
            float s = b1[n];
            for (int k = 0; k < NFEAT; ++k) s = fmaf(f[k], w1[k * 5 + n], s);
            s2 = fmaf(tanhf(s), w2[n], s2);
        }
        ffw = tanhf(s2);
        int qt = qsent[b * TQ + lane];
        logit = idf[b * TQ + lane] * gw[0] + (qt == 0 ? -1e7f : 0.f);
    }
    float m = logit;
#pragma unroll
    for (int t = 1; t < 64; t <<= 1) m = fmaxf(m, __shfl_xor(m, t, 64));
    float e = expf(logit - m);            // inactive lanes -> exp(-inf) = 0
    float se = e, sw = e * ffw;
#pragma unroll
    for (int t = 1; t < 64; t <<= 1) {
        se += __shfl_xor(se, t, 64);
        sw += __shfl_xor(sw, t, 64);
    }
    if (lane == 0) out[b] = (sw / se) * ow[0] + ob[0];
}

extern "C" void kernel_launch(void* const* d_in, const int* in_sizes, int n_in,
                              void* d_out, int out_size, void* d_ws, size_t ws_size,
                              hipStream_t stream) {
    const int*   sent  = (const int*)d_in[0];
    const int*   qsent = (const int*)d_in[1];
    const float* idf   = (const float*)d_in[2];
    const float* emb   = (const float*)d_in[3];
    const float* w1    = (const float*)d_in[4];
    const float* b1    = (const float*)d_in[5];
    const float* w2    = (const float*)d_in[6];
    const float* b2    = (const float*)d_in[7];
    const float* gw    = (const float*)d_in[8];
    const float* ow    = (const float*)d_in[9];
    const float* ob    = (const float*)d_in[10];
    float* out = (float*)d_out;

    char* ws = (char*)d_ws;
    unsigned*  ghist  = (unsigned*)ws;                      // 240 KB
    _Float16*  qfrag  = (_Float16*)(ws + (256 << 10));      // 1.22 MB
    float*     invq   = (float*)(ws + (256 << 10) + (size_t)B_ * QF_BYTES);
    int*       sorted = (int*)(ws + (256 << 10) + (size_t)B_ * QF_BYTES
                               + (size_t)B_ * TQ * 4);      // 1 MB

    k_prep<<<2 * B_, 256, 0, stream>>>(sent, qsent, emb, sorted, qfrag, invq, ghist);
    k_main<<<B_ * (TD / DPB), THREADS, 0, stream>>>(sorted, emb, qfrag, invq, ghist);
    k_finish<<<B_, 64, 0, stream>>>(ghist, qsent, idf, w1, b1, w2, b2, gw, ow, ob, out);
}